// Round 1
// baseline (1044.748 us; speedup 1.0000x reference)
//
#include <hip/hip_runtime.h>

#define B_SZ 32
#define T_SZ 2048
#define XD 64
#define ZD 128
#define H_SZ 512
#define TAU 16

typedef short v8s __attribute__((ext_vector_type(8)));
typedef float v4f __attribute__((ext_vector_type(4)));

__device__ __forceinline__ short f2bf(float f) {
  unsigned u = __float_as_uint(f);
  u = u + 0x7fffu + ((u >> 16) & 1u);
  return (short)(u >> 16);
}

// Fused: influence write (pure block permutation of W1) + v[i,k,d] = sum_h W1*W2.
// 4096 blocks: 4 sub-blocks per (i,k); each wave owns 12 contiguous rows (24 KB).
// 2-row unroll => 64 B/thread in flight; nontemporal on the 805 MB single-use stream.
__global__ __launch_bounds__(256) void transpose_v_kernel(
    const float* __restrict__ W1, const float* __restrict__ W2,
    float* __restrict__ out2, float* __restrict__ v) {
  int blk = blockIdx.x >> 2;       // (i,k) pair: blk = i*16 + k
  int sub = blockIdx.x & 3;        // row-range [sub*48, sub*48+48)
  int i = blk >> 4, k = blk & 15;
  int lane = threadIdx.x & 63;
  int wave = threadIdx.x >> 6;
  const v4f* w2p = (const v4f*)(W2 + (size_t)blk * H_SZ + lane * 8);
  v4f w2a = w2p[0], w2b = w2p[1];
  const float* src = W1 + (size_t)blk * (192 * H_SZ);
  float* dst = out2 + (size_t)(k * 64 + i) * (192 * H_SZ);
  int dstart = sub * 48 + wave * 12;   // 12 contiguous rows per wave

  #pragma unroll
  for (int j = 0; j < 12; j += 2) {
    int d = dstart + j;
    const v4f* s0 = (const v4f*)(src + (size_t)d * H_SZ + lane * 8);
    const v4f* s1 = (const v4f*)(src + (size_t)(d + 1) * H_SZ + lane * 8);
    v4f a0 = __builtin_nontemporal_load(s0);
    v4f b0 = __builtin_nontemporal_load(s0 + 1);
    v4f a1 = __builtin_nontemporal_load(s1);
    v4f b1 = __builtin_nontemporal_load(s1 + 1);
    v4f* o0 = (v4f*)(dst + (size_t)d * H_SZ + lane * 8);
    v4f* o1 = (v4f*)(dst + (size_t)(d + 1) * H_SZ + lane * 8);
    __builtin_nontemporal_store(a0, o0);
    __builtin_nontemporal_store(b0, o0 + 1);
    __builtin_nontemporal_store(a1, o1);
    __builtin_nontemporal_store(b1, o1 + 1);
    float p0 = a0[0]*w2a[0] + a0[1]*w2a[1] + a0[2]*w2a[2] + a0[3]*w2a[3]
             + b0[0]*w2b[0] + b0[1]*w2b[1] + b0[2]*w2b[2] + b0[3]*w2b[3];
    float p1 = a1[0]*w2a[0] + a1[1]*w2a[1] + a1[2]*w2a[2] + a1[3]*w2a[3]
             + b1[0]*w2b[0] + b1[1]*w2b[1] + b1[2]*w2b[2] + b1[3]*w2b[3];
    #pragma unroll
    for (int off = 32; off; off >>= 1) {
      p0 += __shfl_xor(p0, off, 64);
      p1 += __shfl_xor(p1, off, 64);
    }
    if (lane == 0) {
      v[(size_t)blk * 192 + d] = p0;
      v[(size_t)blk * 192 + d + 1] = p1;
    }
  }
}

// Small prep: c[i,k] = b1.W2 + b2 ; csum[i] = sum_k c ; Wb bf16 GEMM weights:
// Wb[i][k*64+d] = v[i,k,d] (d<64),  Wb[i][1024+d] = sum_k v[i,k,64+d]
__global__ __launch_bounds__(256) void prep_kernel(
    const float* __restrict__ b1, const float* __restrict__ W2,
    const float* __restrict__ b2, const float* __restrict__ v,
    float* __restrict__ c, float* __restrict__ csum, short* __restrict__ Wb) {
  int i = blockIdx.x;
  int tid = threadIdx.x;
  int lane = tid & 63;
  int wave = tid >> 6;
  __shared__ float cl[16];
  #pragma unroll
  for (int kk = 0; kk < 4; ++kk) {
    int k = wave * 4 + kk;
    const float* b1p = b1 + (size_t)(i * 16 + k) * H_SZ;
    const float* w2p = W2 + (size_t)(i * 16 + k) * H_SZ;
    float p = 0.f;
    for (int j = lane; j < H_SZ; j += 64) p += b1p[j] * w2p[j];
    #pragma unroll
    for (int off = 32; off; off >>= 1) p += __shfl_xor(p, off, 64);
    if (lane == 0) cl[k] = p + b2[i * 16 + k];
  }
  __syncthreads();
  if (tid < 16) c[i * 16 + tid] = cl[tid];
  if (tid == 0) {
    float s = 0.f;
    #pragma unroll
    for (int k = 0; k < 16; ++k) s += cl[k];
    csum[i] = s;
  }
  for (int idx = tid; idx < 1024; idx += 256) {
    int k = idx >> 6, d = idx & 63;
    Wb[(size_t)i * 1152 + idx] = f2bf(v[(size_t)(i * 16 + k) * 192 + d]);
  }
  for (int idx = tid; idx < 128; idx += 256) {
    float s = 0.f;
    #pragma unroll
    for (int k = 0; k < 16; ++k) s += v[(size_t)(i * 16 + k) * 192 + 64 + idx];
    Wb[(size_t)i * 1152 + 1024 + idx] = f2bf(s);
  }
}

// Main GEMM: out[b,t,i] = sum_K A[t,K]*Wb[i,K] + csum[i], valid for t>=16.
// A's x-part comes from a shifted LDS window (im2col-free causal conv),
// z-part from LDS z-tile. Block = 64 t rows x all 64 i. 4 waves, each 32x32.
__global__ __launch_bounds__(256) void main_gemm_kernel(
    const float* __restrict__ x, const float* __restrict__ z,
    const short* __restrict__ Wb, const float* __restrict__ csum,
    float* __restrict__ out) {
  __shared__ short xs[80 * 72];    // rows t0-16..t0+63, stride 72 (+8 pad: 4-bank rotate)
  __shared__ short zs[64 * 136];   // rows t0..t0+63, stride 136
  int t0 = blockIdx.x * 64;
  int b = blockIdx.y;
  int tid = threadIdx.x;

  #pragma unroll
  for (int it = 0; it < 5; ++it) {
    int idx = tid + it * 256;      // 0..1279 : 80 rows x 16 float4
    int r = idx >> 4;
    int c4 = (idx & 15) * 4;
    int t = t0 - 16 + r;
    float4 val = make_float4(0.f, 0.f, 0.f, 0.f);
    if (t >= 0) val = *(const float4*)(x + ((size_t)b * T_SZ + t) * XD + c4);
    short4 sv;
    sv.x = f2bf(val.x); sv.y = f2bf(val.y); sv.z = f2bf(val.z); sv.w = f2bf(val.w);
    *(short4*)(xs + r * 72 + c4) = sv;
  }
  #pragma unroll
  for (int it = 0; it < 8; ++it) {
    int idx = tid + it * 256;      // 0..2047 : 64 rows x 32 float4
    int r = idx >> 5;
    int c4 = (idx & 31) * 4;
    float4 val = *(const float4*)(z + ((size_t)b * T_SZ + t0 + r) * ZD + c4);
    short4 sv;
    sv.x = f2bf(val.x); sv.y = f2bf(val.y); sv.z = f2bf(val.z); sv.w = f2bf(val.w);
    *(short4*)(zs + r * 136 + c4) = sv;
  }
  __syncthreads();

  int lane = tid & 63;
  int wave = tid >> 6;
  int l15 = lane & 15;
  int quad = lane >> 4;
  int tg = wave >> 1;              // which 32-row t half
  int ig = wave & 1;               // which 32-col i half

  v4f acc00 = {0.f,0.f,0.f,0.f}, acc01 = {0.f,0.f,0.f,0.f};
  v4f acc10 = {0.f,0.f,0.f,0.f}, acc11 = {0.f,0.f,0.f,0.f};
  const short* wb0 = Wb + (size_t)(ig * 32 + l15) * 1152 + quad * 8;
  const short* wb1 = wb0 + 16 * 1152;

  // x part: K=1024 as 32 steps of 32 (k_shift = s>>1, d0 = (s&1)*32)
  #pragma unroll 4
  for (int s = 0; s < 32; ++s) {
    int ks = s >> 1;
    int d0 = (s & 1) * 32;
    int rb = 16 + tg * 32 + l15 - 1 - ks;
    v8s a0 = *(const v8s*)(xs + rb * 72 + d0 + quad * 8);
    v8s a1 = *(const v8s*)(xs + (rb + 16) * 72 + d0 + quad * 8);
    v8s b0 = *(const v8s*)(wb0 + s * 32);
    v8s b1 = *(const v8s*)(wb1 + s * 32);
    acc00 = __builtin_amdgcn_mfma_f32_16x16x32_bf16(a0, b0, acc00, 0, 0, 0);
    acc01 = __builtin_amdgcn_mfma_f32_16x16x32_bf16(a0, b1, acc01, 0, 0, 0);
    acc10 = __builtin_amdgcn_mfma_f32_16x16x32_bf16(a1, b0, acc10, 0, 0, 0);
    acc11 = __builtin_amdgcn_mfma_f32_16x16x32_bf16(a1, b1, acc11, 0, 0, 0);
  }
  // z part: K=128 as 4 steps of 32
  #pragma unroll
  for (int s = 0; s < 4; ++s) {
    int rb = tg * 32 + l15;
    v8s a0 = *(const v8s*)(zs + rb * 136 + s * 32 + quad * 8);
    v8s a1 = *(const v8s*)(zs + (rb + 16) * 136 + s * 32 + quad * 8);
    v8s b0 = *(const v8s*)(wb0 + 1024 + s * 32);
    v8s b1 = *(const v8s*)(wb1 + 1024 + s * 32);
    acc00 = __builtin_amdgcn_mfma_f32_16x16x32_bf16(a0, b0, acc00, 0, 0, 0);
    acc01 = __builtin_amdgcn_mfma_f32_16x16x32_bf16(a0, b1, acc01, 0, 0, 0);
    acc10 = __builtin_amdgcn_mfma_f32_16x16x32_bf16(a1, b0, acc10, 0, 0, 0);
    acc11 = __builtin_amdgcn_mfma_f32_16x16x32_bf16(a1, b1, acc11, 0, 0, 0);
  }

  // epilogue: D row = quad*4+reg (t), col = l15 (i)
  int trow = t0 + tg * 32 + quad * 4;
  int ic0 = ig * 32 + l15;
  float cs0 = csum[ic0];
  float cs1 = csum[ic0 + 16];
  float* outb = out + (size_t)b * T_SZ * XD;
  #pragma unroll
  for (int r = 0; r < 4; ++r) {
    outb[(size_t)(trow + r) * XD + ic0]       = acc00[r] + cs0;
    outb[(size_t)(trow + r) * XD + ic0 + 16]  = acc01[r] + cs1;
    outb[(size_t)(trow + 16 + r) * XD + ic0]      = acc10[r] + cs0;
    outb[(size_t)(trow + 16 + r) * XD + ic0 + 16] = acc11[r] + cs1;
  }
}

// Exact f32 recompute of t<16 edge (partial-k validity for z and c terms).
__global__ __launch_bounds__(1024) void fixup_kernel(
    const float* __restrict__ x, const float* __restrict__ z,
    const float* __restrict__ v, const float* __restrict__ c,
    float* __restrict__ out) {
  int b = blockIdx.x;
  __shared__ float xl[15 * 64];
  __shared__ float zl[16 * 128];
  for (int idx = threadIdx.x; idx < 15 * 64; idx += 1024)
    xl[idx] = x[(size_t)b * T_SZ * XD + idx];
  for (int idx = threadIdx.x; idx < 16 * 128; idx += 1024)
    zl[idx] = z[(size_t)b * T_SZ * ZD + idx];
  __syncthreads();
  int t = threadIdx.x >> 6;       // 0..15
  int i = threadIdx.x & 63;       // 0..63
  float sacc = 0.f;
  for (int k = 0; k < t; ++k) {   // valid: k <= t-1
    const float* vp = v + (size_t)(i * 16 + k) * 192;
    const float* xr = xl + (t - 1 - k) * 64;
    float d1 = 0.f;
    #pragma unroll 8
    for (int d = 0; d < 64; ++d) d1 += xr[d] * vp[d];
    const float* zr = zl + t * 128;
    float d2 = 0.f;
    #pragma unroll 8
    for (int d = 0; d < 128; ++d) d2 += zr[d] * vp[64 + d];
    sacc += d1 + d2 + c[i * 16 + k];
  }
  out[((size_t)b * T_SZ + t) * XD + i] = sacc;
}

extern "C" void kernel_launch(void* const* d_in, const int* in_sizes, int n_in,
                              void* d_out, int out_size, void* d_ws, size_t ws_size,
                              hipStream_t stream) {
  const float* z_in = (const float*)d_in[0];
  const float* x_in = (const float*)d_in[1];
  const float* W1   = (const float*)d_in[2];
  const float* b1   = (const float*)d_in[3];
  const float* W2   = (const float*)d_in[4];
  const float* b2   = (const float*)d_in[5];
  float* out  = (float*)d_out;                      // (B,T,64) = 4194304 floats
  float* out2 = out + (size_t)B_SZ * T_SZ * XD;     // influence (16,64,192,512)

  char* ws = (char*)d_ws;
  float* v    = (float*)ws;                         // 64*16*192 f32 = 786432 B
  float* cbuf = (float*)(ws + 786432);              // 1024 f32
  float* csum = (float*)(ws + 790528);              // 64 f32
  short* Wb   = (short*)(ws + 790784);              // 64*1152 bf16 = 147456 B

  transpose_v_kernel<<<4096, 256, 0, stream>>>(W1, W2, out2, v);
  prep_kernel<<<64, 256, 0, stream>>>(b1, W2, b2, v, cbuf, csum, Wb);
  main_gemm_kernel<<<dim3(T_SZ / 64, B_SZ), 256, 0, stream>>>(x_in, z_in, Wb, csum, out);
  fixup_kernel<<<B_SZ, 1024, 0, stream>>>(x_in, z_in, v, cbuf, out);
}

// Round 2
// 835.176 us; speedup vs baseline: 1.2509x; 1.2509x over previous
//
#include <hip/hip_runtime.h>

#define B_SZ 32
#define T_SZ 2048
#define XD 64
#define ZD 128
#define H_SZ 512
#define TAU 16

typedef short v8s __attribute__((ext_vector_type(8)));
typedef float v4f __attribute__((ext_vector_type(4)));

__device__ __forceinline__ short f2bf(float f) {
  unsigned u = __float_as_uint(f);
  u = u + 0x7fffu + ((u >> 16) & 1u);
  return (short)(u >> 16);
}

// Fused: influence write (pure block permutation of W1) + v[i,k,d] = sum_h W1*W2.
// 4096 blocks: 4 sub-blocks per (i,k); each wave owns 12 contiguous rows.
// Lane-contiguous per instruction: lane l covers bytes [l*16, l*16+16) of each
// 1 KB half-row => every store instruction covers 16 FULL 64B lines (no
// partial-line NT write amplification). 12 loads in flight per half.
__global__ __launch_bounds__(256) void transpose_v_kernel(
    const float* __restrict__ W1, const float* __restrict__ W2,
    float* __restrict__ out2, float* __restrict__ v) {
  int blk = blockIdx.x >> 2;       // (i,k) pair: blk = i*16 + k
  int sub = blockIdx.x & 3;        // row-range [sub*48, sub*48+48)
  int i = blk >> 4, k = blk & 15;
  int lane = threadIdx.x & 63;
  int wave = threadIdx.x >> 6;
  // lane l owns h-elements [l*4, l*4+4) (first half-row) and [256+l*4, ...)
  v4f w2a = *(const v4f*)(W2 + (size_t)blk * H_SZ + lane * 4);
  v4f w2b = *(const v4f*)(W2 + (size_t)blk * H_SZ + 256 + lane * 4);
  const float* src = W1 + (size_t)blk * (192 * H_SZ) + lane * 4;
  float* dst = out2 + (size_t)(k * 64 + i) * (192 * H_SZ) + lane * 4;
  int dstart = sub * 48 + wave * 12;   // 12 contiguous rows per wave
  float p[12];

  #pragma unroll
  for (int h = 0; h < 2; ++h) {        // two halves of 6 rows each
    v4f A[6], Bv[6];
    #pragma unroll
    for (int r = 0; r < 6; ++r) {
      int d = dstart + h * 6 + r;
      const v4f* s = (const v4f*)(src + (size_t)d * H_SZ);
      A[r]  = __builtin_nontemporal_load(s);
      Bv[r] = __builtin_nontemporal_load((const v4f*)(src + (size_t)d * H_SZ + 256));
    }
    #pragma unroll
    for (int r = 0; r < 6; ++r) {
      int d = dstart + h * 6 + r;
      __builtin_nontemporal_store(A[r],  (v4f*)(dst + (size_t)d * H_SZ));
      __builtin_nontemporal_store(Bv[r], (v4f*)(dst + (size_t)d * H_SZ + 256));
      p[h * 6 + r] = A[r][0]*w2a[0] + A[r][1]*w2a[1] + A[r][2]*w2a[2] + A[r][3]*w2a[3]
                   + Bv[r][0]*w2b[0] + Bv[r][1]*w2b[1] + Bv[r][2]*w2b[2] + Bv[r][3]*w2b[3];
    }
  }
  #pragma unroll
  for (int r = 0; r < 12; ++r) {
    float pr = p[r];
    #pragma unroll
    for (int off = 32; off; off >>= 1) pr += __shfl_xor(pr, off, 64);
    if (lane == 0) v[(size_t)blk * 192 + dstart + r] = pr;
  }
}

// Small prep: c[i,k] = b1.W2 + b2 ; csum[i] = sum_k c ; Wb bf16 GEMM weights:
// Wb[i][k*64+d] = v[i,k,d] (d<64),  Wb[i][1024+d] = sum_k v[i,k,64+d]
__global__ __launch_bounds__(256) void prep_kernel(
    const float* __restrict__ b1, const float* __restrict__ W2,
    const float* __restrict__ b2, const float* __restrict__ v,
    float* __restrict__ c, float* __restrict__ csum, short* __restrict__ Wb) {
  int i = blockIdx.x;
  int tid = threadIdx.x;
  int lane = tid & 63;
  int wave = tid >> 6;
  __shared__ float cl[16];
  #pragma unroll
  for (int kk = 0; kk < 4; ++kk) {
    int k = wave * 4 + kk;
    const float* b1p = b1 + (size_t)(i * 16 + k) * H_SZ;
    const float* w2p = W2 + (size_t)(i * 16 + k) * H_SZ;
    float p = 0.f;
    for (int j = lane; j < H_SZ; j += 64) p += b1p[j] * w2p[j];
    #pragma unroll
    for (int off = 32; off; off >>= 1) p += __shfl_xor(p, off, 64);
    if (lane == 0) cl[k] = p + b2[i * 16 + k];
  }
  __syncthreads();
  if (tid < 16) c[i * 16 + tid] = cl[tid];
  if (tid == 0) {
    float s = 0.f;
    #pragma unroll
    for (int k = 0; k < 16; ++k) s += cl[k];
    csum[i] = s;
  }
  for (int idx = tid; idx < 1024; idx += 256) {
    int k = idx >> 6, d = idx & 63;
    Wb[(size_t)i * 1152 + idx] = f2bf(v[(size_t)(i * 16 + k) * 192 + d]);
  }
  for (int idx = tid; idx < 128; idx += 256) {
    float s = 0.f;
    #pragma unroll
    for (int k = 0; k < 16; ++k) s += v[(size_t)(i * 16 + k) * 192 + 64 + idx];
    Wb[(size_t)i * 1152 + 1024 + idx] = f2bf(s);
  }
}

// Main GEMM: out[b,t,i] = sum_K A[t,K]*Wb[i,K] + csum[i], valid for t>=16.
// A's x-part comes from a shifted LDS window (im2col-free causal conv),
// z-part from LDS z-tile. Block = 64 t rows x all 64 i. 4 waves, each 32x32.
__global__ __launch_bounds__(256) void main_gemm_kernel(
    const float* __restrict__ x, const float* __restrict__ z,
    const short* __restrict__ Wb, const float* __restrict__ csum,
    float* __restrict__ out) {
  __shared__ short xs[80 * 72];    // rows t0-16..t0+63, stride 72 (+8 pad: 4-bank rotate)
  __shared__ short zs[64 * 136];   // rows t0..t0+63, stride 136
  int t0 = blockIdx.x * 64;
  int b = blockIdx.y;
  int tid = threadIdx.x;

  #pragma unroll
  for (int it = 0; it < 5; ++it) {
    int idx = tid + it * 256;      // 0..1279 : 80 rows x 16 float4
    int r = idx >> 4;
    int c4 = (idx & 15) * 4;
    int t = t0 - 16 + r;
    float4 val = make_float4(0.f, 0.f, 0.f, 0.f);
    if (t >= 0) val = *(const float4*)(x + ((size_t)b * T_SZ + t) * XD + c4);
    short4 sv;
    sv.x = f2bf(val.x); sv.y = f2bf(val.y); sv.z = f2bf(val.z); sv.w = f2bf(val.w);
    *(short4*)(xs + r * 72 + c4) = sv;
  }
  #pragma unroll
  for (int it = 0; it < 8; ++it) {
    int idx = tid + it * 256;      // 0..2047 : 64 rows x 32 float4
    int r = idx >> 5;
    int c4 = (idx & 31) * 4;
    float4 val = *(const float4*)(z + ((size_t)b * T_SZ + t0 + r) * ZD + c4);
    short4 sv;
    sv.x = f2bf(val.x); sv.y = f2bf(val.y); sv.z = f2bf(val.z); sv.w = f2bf(val.w);
    *(short4*)(zs + r * 136 + c4) = sv;
  }
  __syncthreads();

  int lane = tid & 63;
  int wave = tid >> 6;
  int l15 = lane & 15;
  int quad = lane >> 4;
  int tg = wave >> 1;              // which 32-row t half
  int ig = wave & 1;               // which 32-col i half

  v4f acc00 = {0.f,0.f,0.f,0.f}, acc01 = {0.f,0.f,0.f,0.f};
  v4f acc10 = {0.f,0.f,0.f,0.f}, acc11 = {0.f,0.f,0.f,0.f};
  const short* wb0 = Wb + (size_t)(ig * 32 + l15) * 1152 + quad * 8;
  const short* wb1 = wb0 + 16 * 1152;

  // x part: K=1024 as 32 steps of 32 (k_shift = s>>1, d0 = (s&1)*32)
  #pragma unroll 4
  for (int s = 0; s < 32; ++s) {
    int ks = s >> 1;
    int d0 = (s & 1) * 32;
    int rb = 16 + tg * 32 + l15 - 1 - ks;
    v8s a0 = *(const v8s*)(xs + rb * 72 + d0 + quad * 8);
    v8s a1 = *(const v8s*)(xs + (rb + 16) * 72 + d0 + quad * 8);
    v8s b0 = *(const v8s*)(wb0 + s * 32);
    v8s b1 = *(const v8s*)(wb1 + s * 32);
    acc00 = __builtin_amdgcn_mfma_f32_16x16x32_bf16(a0, b0, acc00, 0, 0, 0);
    acc01 = __builtin_amdgcn_mfma_f32_16x16x32_bf16(a0, b1, acc01, 0, 0, 0);
    acc10 = __builtin_amdgcn_mfma_f32_16x16x32_bf16(a1, b0, acc10, 0, 0, 0);
    acc11 = __builtin_amdgcn_mfma_f32_16x16x32_bf16(a1, b1, acc11, 0, 0, 0);
  }
  // z part: K=128 as 4 steps of 32
  #pragma unroll
  for (int s = 0; s < 4; ++s) {
    int rb = tg * 32 + l15;
    v8s a0 = *(const v8s*)(zs + rb * 136 + s * 32 + quad * 8);
    v8s a1 = *(const v8s*)(zs + (rb + 16) * 136 + s * 32 + quad * 8);
    v8s b0 = *(const v8s*)(wb0 + 1024 + s * 32);
    v8s b1 = *(const v8s*)(wb1 + 1024 + s * 32);
    acc00 = __builtin_amdgcn_mfma_f32_16x16x32_bf16(a0, b0, acc00, 0, 0, 0);
    acc01 = __builtin_amdgcn_mfma_f32_16x16x32_bf16(a0, b1, acc01, 0, 0, 0);
    acc10 = __builtin_amdgcn_mfma_f32_16x16x32_bf16(a1, b0, acc10, 0, 0, 0);
    acc11 = __builtin_amdgcn_mfma_f32_16x16x32_bf16(a1, b1, acc11, 0, 0, 0);
  }

  // epilogue: D row = quad*4+reg (t), col = l15 (i)
  int trow = t0 + tg * 32 + quad * 4;
  int ic0 = ig * 32 + l15;
  float cs0 = csum[ic0];
  float cs1 = csum[ic0 + 16];
  float* outb = out + (size_t)b * T_SZ * XD;
  #pragma unroll
  for (int r = 0; r < 4; ++r) {
    outb[(size_t)(trow + r) * XD + ic0]       = acc00[r] + cs0;
    outb[(size_t)(trow + r) * XD + ic0 + 16]  = acc01[r] + cs1;
    outb[(size_t)(trow + 16 + r) * XD + ic0]      = acc10[r] + cs0;
    outb[(size_t)(trow + 16 + r) * XD + ic0 + 16] = acc11[r] + cs1;
  }
}

// Exact f32 recompute of t<16 edge (partial-k validity for z and c terms).
// v[:,k,:] staged in LDS per k (coalesced global reads; padded stride 193
// => conflict-free lane-strided LDS reads). Same math as before.
__global__ __launch_bounds__(1024) void fixup_kernel(
    const float* __restrict__ x, const float* __restrict__ z,
    const float* __restrict__ v, const float* __restrict__ c,
    float* __restrict__ out) {
  int b = blockIdx.x;
  __shared__ float xl[15 * 64];
  __shared__ float zl[16 * 128];
  __shared__ float cl[64 * 17];
  __shared__ float vl[64 * 193];
  for (int idx = threadIdx.x; idx < 15 * 64; idx += 1024)
    xl[idx] = x[(size_t)b * T_SZ * XD + idx];
  for (int idx = threadIdx.x; idx < 16 * 128; idx += 1024)
    zl[idx] = z[(size_t)b * T_SZ * ZD + idx];
  if (threadIdx.x < 1024) {
    int ii = threadIdx.x >> 4, kk = threadIdx.x & 15;
    cl[ii * 17 + kk] = c[ii * 16 + kk];
  }
  int t = threadIdx.x >> 6;       // 0..15 (wave-uniform)
  int i = threadIdx.x & 63;       // 0..63
  float sacc = 0.f;
  for (int k = 0; k < 15; ++k) {
    __syncthreads();              // covers initial staging + vl reuse
    for (int idx = threadIdx.x; idx < 64 * 192; idx += 1024) {
      int ii = idx / 192, dd = idx - ii * 192;
      vl[ii * 193 + dd] = v[(size_t)(ii * 16 + k) * 192 + dd];
    }
    __syncthreads();
    if (k < t) {
      const float* vp = vl + i * 193;
      const float* xr = xl + (t - 1 - k) * 64;
      float d1 = 0.f;
      #pragma unroll 8
      for (int d = 0; d < 64; ++d) d1 += xr[d] * vp[d];
      const float* zr = zl + t * 128;
      float d2 = 0.f;
      #pragma unroll 8
      for (int d = 0; d < 128; ++d) d2 += zr[d] * vp[64 + d];
      sacc += d1 + d2 + cl[i * 17 + k];
    }
  }
  out[((size_t)b * T_SZ + t) * XD + i] = sacc;
}

extern "C" void kernel_launch(void* const* d_in, const int* in_sizes, int n_in,
                              void* d_out, int out_size, void* d_ws, size_t ws_size,
                              hipStream_t stream) {
  const float* z_in = (const float*)d_in[0];
  const float* x_in = (const float*)d_in[1];
  const float* W1   = (const float*)d_in[2];
  const float* b1   = (const float*)d_in[3];
  const float* W2   = (const float*)d_in[4];
  const float* b2   = (const float*)d_in[5];
  float* out  = (float*)d_out;                      // (B,T,64) = 4194304 floats
  float* out2 = out + (size_t)B_SZ * T_SZ * XD;     // influence (16,64,192,512)

  char* ws = (char*)d_ws;
  float* v    = (float*)ws;                         // 64*16*192 f32 = 786432 B
  float* cbuf = (float*)(ws + 786432);              // 1024 f32
  float* csum = (float*)(ws + 790528);              // 64 f32
  short* Wb   = (short*)(ws + 790784);              // 64*1152 bf16 = 147456 B

  transpose_v_kernel<<<4096, 256, 0, stream>>>(W1, W2, out2, v);
  prep_kernel<<<64, 256, 0, stream>>>(b1, W2, b2, v, cbuf, csum, Wb);
  main_gemm_kernel<<<dim3(T_SZ / 64, B_SZ), 256, 0, stream>>>(x_in, z_in, Wb, csum, out);
  fixup_kernel<<<B_SZ, 1024, 0, stream>>>(x_in, z_in, v, cbuf, out);
}